// Round 2
// baseline (422.287 us; speedup 1.0000x reference)
//
#include <hip/hip_runtime.h>

// ---------------------------------------------------------------------------
// PGN step, fused. All tensors fp32 in HBM; bf16 MFMA internally.
// B=2, N=512, F=MID=OUT=128, Z=256.
//
// out[b,j] = relu( h1[b,j] + (msg1[b,j] + msgg[b] + be +
//                  max_{i: adj[b,i,j]>0}( msg2[b,i] + E[b,i,j,:]@We )) @ Wo2 + bo2 )
// where h1 = z@Wo1+bo1, msg1 = z@W1+b1, msg2 = z@W2+b2, msgg = g@Wg+bg,
//       z = cat(node, hidden).
// ---------------------------------------------------------------------------

typedef __bf16 bf16x8 __attribute__((ext_vector_type(8)));
typedef float  f32x4  __attribute__((ext_vector_type(4)));

#define MFMA16(a,b,c) __builtin_amdgcn_mfma_f32_16x16x32_bf16(a,b,c,0,0,0)

union BFrag { bf16x8 v; unsigned short s[8]; unsigned u[4]; };

// pack two f32 -> two bf16 (truncate) in one v_perm_b32
__device__ __forceinline__ unsigned packbf(float lo, float hi){
  return __builtin_amdgcn_perm(__builtin_bit_cast(unsigned, hi),
                               __builtin_bit_cast(unsigned, lo), 0x07060302u);
}
__device__ __forceinline__ unsigned short f2bt(float f){   // truncate
  return (unsigned short)(__builtin_bit_cast(unsigned, f) >> 16);
}
__device__ __forceinline__ unsigned short f2b(float f){    // RNE
  unsigned u = __builtin_bit_cast(unsigned, f);
  u = u + 0x7FFFu + ((u >> 16) & 1u);
  return (unsigned short)(u >> 16);
}

// workspace layout (float elements)
#define WS_MS2  0            // msg_2  (B*N*128)
#define WS_MS1  131072       // msg_1  (B*N*128)
#define WS_H1   262144       // h_1    (B*N*128)
#define WS_MSGG 393216       // msg_g  (B*128)
#define WS_PART 393472       // partial maxes: [b][jt:32][s:8][16][128]

// ---------------------------------------------------------------------------
// K1: msg_1 / msg_2 / h_1 (1024x256x128 GEMMs, 16-row tiles, 1 wave/block)
//     + msg_g (blocks 192,193).
// MFMA frag conventions (m89-verified):
//   A: lane holds A[m=lane&15][k=(lane>>4)*8+j]
//   B: lane holds B[k=(lane>>4)*8+j][n=lane&15]
//   D: lane reg r holds D[row=(lane>>4)*4+r][col=lane&15]
// ---------------------------------------------------------------------------
__global__ __launch_bounds__(64) void k1_small(
    const float* __restrict__ node,
    const float* __restrict__ hidden,
    const float* __restrict__ graph,
    const float* __restrict__ W1, const float* __restrict__ b1,
    const float* __restrict__ W2, const float* __restrict__ b2,
    const float* __restrict__ Wo1,const float* __restrict__ bo1,
    const float* __restrict__ Wg, const float* __restrict__ bg,
    float* __restrict__ ws)
{
  int bid  = blockIdx.x;
  int lane = threadIdx.x;
  int col = lane & 15, quad = lane >> 4;

  if (bid < 192) {
    int mat = bid >> 6;              // 0: W1->msg1, 1: W2->msg2, 2: Wo1->h1
    int rt  = bid & 63;
    int r0  = rt * 16;               // flat row b*512+n
    const float* W  = (mat==0) ? W1 : (mat==1) ? W2 : Wo1;
    const float* bb = (mat==0) ? b1 : (mat==1) ? b2 : bo1;
    float* dst = ws + ((mat==0) ? WS_MS1 : (mat==1) ? WS_MS2 : WS_H1);

    // A-frags from z = cat(node, hidden): kk<4 -> node, kk>=4 -> hidden
    bf16x8 a[8];
    long rowb = (long)(r0 + col) * 128;
#pragma unroll
    for (int kk = 0; kk < 8; ++kk) {
      const float* src = (kk < 4) ? node : hidden;
      int f = (kk & 3) * 32 + quad * 8;
      f32x4 v0 = *(const f32x4*)(src + rowb + f);
      f32x4 v1 = *(const f32x4*)(src + rowb + f + 4);
      BFrag t;
      t.u[0] = packbf(v0[0], v0[1]); t.u[1] = packbf(v0[2], v0[3]);
      t.u[2] = packbf(v1[0], v1[1]); t.u[3] = packbf(v1[2], v1[3]);
      a[kk] = t.v;
    }
    f32x4 acc[8];
#pragma unroll
    for (int nt = 0; nt < 8; ++nt) acc[nt] = (f32x4)0.f;
#pragma unroll
    for (int kk = 0; kk < 8; ++kk) {
      BFrag bf[8];
#pragma unroll
      for (int nt = 0; nt < 8; ++nt)
#pragma unroll
        for (int j = 0; j < 8; ++j)
          bf[nt].s[j] = f2bt(W[(kk*32 + quad*8 + j)*128 + nt*16 + col]);
#pragma unroll
      for (int nt = 0; nt < 8; ++nt) acc[nt] = MFMA16(a[kk], bf[nt].v, acc[nt]);
    }
#pragma unroll
    for (int nt = 0; nt < 8; ++nt) {
      float bv = bb[nt*16 + col];
#pragma unroll
      for (int r = 0; r < 4; ++r) {
        int row = r0 + quad*4 + r;
        dst[(long)row*128 + nt*16 + col] = acc[nt][r] + bv;
      }
    }
  } else {
    // msg_g[b] = graph_fts[b] @ Wg + bg   (one wave; 2 outputs/lane)
    int b = bid - 192;
    float a0 = 0.f, a1 = 0.f;
    for (int k = 0; k < 128; ++k) {
      float g = graph[b*128 + k];
      a0 += g * Wg[k*128 + lane];
      a1 += g * Wg[k*128 + 64 + lane];
    }
    ws[WS_MSGG + b*128 + lane]      = a0 + bg[lane];
    ws[WS_MSGG + b*128 + 64 + lane] = a1 + bg[64 + lane];
  }
}

// ---------------------------------------------------------------------------
// K2: the hot loop. Block = (b, 16-wide j-tile, 64-wide i-chunk); 4 waves,
// wave w covers 16 i's. We^T staged to LDS as bf16 once; B-frags read from
// LDS each iteration (ds_read_b128; keeps VGPRs ~190 -> 2 blocks/CU).
// Per i: 8x16B fp32 A loads prefetched one iteration ahead, in-register
// pack to bf16 (v_perm), acc init = msg2 + (adj-1)*1e6, 32 MFMAs, f32 max.
// ---------------------------------------------------------------------------
#define LDS_PITCH 136   // shorts; 272 B rows: 16B-aligned, b128-clean

__global__ __launch_bounds__(256, 2) void k2_main(
    const float* __restrict__ E,
    const float* __restrict__ We,
    const float* __restrict__ adj,
    const float* __restrict__ msg2,
    float* __restrict__ part)
{
  __shared__ alignas(16) unsigned short smem[LDS_PITCH * 128]; // 34816 B

  int bid = blockIdx.x;
  int jt = bid & 31, s = (bid >> 5) & 7, b = bid >> 8;
  int tid = threadIdx.x;
  int w = tid >> 6, lane = tid & 63;
  int col = lane & 15, quad = lane >> 4;
  int j0 = jt * 16;

  // --- stage We^T[m][k] (bf16) into LDS: coalesced fp32 read, scatter write
#pragma unroll
  for (int p = 0; p < 8; ++p) {
    int g = p*2048 + tid*8;
    int k = g >> 7, m = g & 127;
    f32x4 v0 = *(const f32x4*)(We + k*128 + m);
    f32x4 v1 = *(const f32x4*)(We + k*128 + m + 4);
    unsigned short sv[8] = { f2b(v0[0]), f2b(v0[1]), f2b(v0[2]), f2b(v0[3]),
                             f2b(v1[0]), f2b(v1[1]), f2b(v1[2]), f2b(v1[3]) };
#pragma unroll
    for (int e = 0; e < 8; ++e) smem[(m+e)*LDS_PITCH + k] = sv[e];
  }
  __syncthreads();

  f32x4 mx[8];
#pragma unroll
  for (int nt = 0; nt < 8; ++nt) mx[nt] = (f32x4)(-1.0e6f);

  int i0 = s*64 + w*16;

  // prefetch state: raw fp32 E row chunk + adj + msg2
  f32x4 rv[8]; float4 av; float m2[8];
  {
    const float* ep = E + ((long)(b*512 + i0)*512 + j0 + col)*128;
#pragma unroll
    for (int kk = 0; kk < 4; ++kk) {
      rv[2*kk]   = *(const f32x4*)(ep + kk*32 + quad*8);
      rv[2*kk+1] = *(const f32x4*)(ep + kk*32 + quad*8 + 4);
    }
    av = *(const float4*)(adj + (long)(b*512 + i0)*512 + j0 + quad*4);
    const float* mp = msg2 + (long)(b*512 + i0)*128 + col;
#pragma unroll
    for (int nt = 0; nt < 8; ++nt) m2[nt] = mp[nt*16];
  }

#pragma unroll 1
  for (int ii = 0; ii < 16; ++ii) {
    int inx = i0 + ((ii < 15) ? ii + 1 : ii);   // clamped prefetch

    f32x4 nrv[8]; float4 nav; float nm2[8];
    {
      const float* ep = E + ((long)(b*512 + inx)*512 + j0 + col)*128;
#pragma unroll
      for (int kk = 0; kk < 4; ++kk) {
        nrv[2*kk]   = *(const f32x4*)(ep + kk*32 + quad*8);
        nrv[2*kk+1] = *(const f32x4*)(ep + kk*32 + quad*8 + 4);
      }
      nav = *(const float4*)(adj + (long)(b*512 + inx)*512 + j0 + quad*4);
      const float* mp = msg2 + (long)(b*512 + inx)*128 + col;
#pragma unroll
      for (int nt = 0; nt < 8; ++nt) nm2[nt] = mp[nt*16];
    }

    // pack current A-frags (truncating f32->bf16, 4 v_perm per frag)
    BFrag a[4];
#pragma unroll
    for (int kk = 0; kk < 4; ++kk) {
      a[kk].u[0] = packbf(rv[2*kk][0],   rv[2*kk][1]);
      a[kk].u[1] = packbf(rv[2*kk][2],   rv[2*kk][3]);
      a[kk].u[2] = packbf(rv[2*kk+1][0], rv[2*kk+1][1]);
      a[kk].u[3] = packbf(rv[2*kk+1][2], rv[2*kk+1][3]);
    }

    // mask bias: adj in {0,1} -> 0 or -1e6 (diag guarantees a hit)
    f32x4 biasv;
    biasv[0] = av.x*1.0e6f - 1.0e6f;
    biasv[1] = av.y*1.0e6f - 1.0e6f;
    biasv[2] = av.z*1.0e6f - 1.0e6f;
    biasv[3] = av.w*1.0e6f - 1.0e6f;

    f32x4 T[8];
#pragma unroll
    for (int nt = 0; nt < 8; ++nt) T[nt] = biasv + m2[nt];   // acc init
#pragma unroll
    for (int kk = 0; kk < 4; ++kk)
#pragma unroll
      for (int nt = 0; nt < 8; ++nt) {
        bf16x8 bb = *(const bf16x8*)(&smem[(nt*16 + col)*LDS_PITCH + kk*32 + quad*8]);
        T[nt] = MFMA16(a[kk].v, bb, T[nt]);
      }
#pragma unroll
    for (int nt = 0; nt < 8; ++nt)
#pragma unroll
      for (int r = 0; r < 4; ++r)
        mx[nt][r] = fmaxf(mx[nt][r], T[nt][r]);

#pragma unroll
    for (int q = 0; q < 8; ++q) rv[q] = nrv[q];
    av = nav;
#pragma unroll
    for (int nt = 0; nt < 8; ++nt) m2[nt] = nm2[nt];
  }

  // --- cross-wave max combine via LDS (reuse We^T region), store partial
  __syncthreads();
  float* red = (float*)smem;
#pragma unroll
  for (int nt = 0; nt < 8; ++nt)
#pragma unroll
    for (int r = 0; r < 4; ++r)
      red[(w*16 + quad*4 + r)*128 + nt*16 + col] = mx[nt][r];   // [w][j][n]
  __syncthreads();
  {
    int e0 = tid * 8;
    const f32x4* r4 = (const f32x4*)red;
    f32x4 v0 = r4[e0 >> 2], v1 = r4[(e0 >> 2) + 1];
#pragma unroll
    for (int ww = 1; ww < 4; ++ww) {
      f32x4 u0 = r4[(ww*2048 + e0) >> 2];
      f32x4 u1 = r4[((ww*2048 + e0) >> 2) + 1];
#pragma unroll
      for (int r = 0; r < 4; ++r) { v0[r] = fmaxf(v0[r], u0[r]); v1[r] = fmaxf(v1[r], u1[r]); }
    }
    f32x4* pp = (f32x4*)(part + ((long)((b*32 + jt)*8 + s))*2048 + e0);
    pp[0] = v0; pp[1] = v1;
  }
}

// ---------------------------------------------------------------------------
// K3: combine 8 partials -> + msg1 + msgg + be -> bf16 -> @Wo2 (MFMA)
//     -> + h1 + bo2 -> relu -> fp32 out.  64 blocks x 1 wave.
// ---------------------------------------------------------------------------
__global__ __launch_bounds__(64) void k3_out(
    const float* __restrict__ ws,
    const float* __restrict__ Wo2,
    const float* __restrict__ be,
    const float* __restrict__ bo2,
    float* __restrict__ out)
{
  int bid = blockIdx.x;
  int b = bid >> 5, jt = bid & 31, j0 = jt * 16;
  int lane = threadIdx.x, col = lane & 15, quad = lane >> 4;

  const float* part = ws + WS_PART + ((long)((b*32 + jt)*8))*2048;
  const float* msg1 = ws + WS_MS1;
  const float* msgg = ws + WS_MSGG + b*128;
  const float* h1   = ws + WS_H1;

  // A-frags of msgs_red: lane row = col, k = kk*32+quad*8+e
  BFrag af[4];
#pragma unroll
  for (int kk = 0; kk < 4; ++kk) {
    int off = kk*32 + quad*8;
    const float* p0 = part + col*128 + off;
    f32x4 v0 = *(const f32x4*)(p0);
    f32x4 v1 = *(const f32x4*)(p0 + 4);
#pragma unroll
    for (int s = 1; s < 8; ++s) {
      f32x4 u0 = *(const f32x4*)(p0 + s*2048);
      f32x4 u1 = *(const f32x4*)(p0 + s*2048 + 4);
#pragma unroll
      for (int r = 0; r < 4; ++r) { v0[r] = fmaxf(v0[r], u0[r]); v1[r] = fmaxf(v1[r], u1[r]); }
    }
    const float* m1 = msg1 + (long)(b*512 + j0 + col)*128 + off;
    f32x4 w0 = *(const f32x4*)m1, w1 = *(const f32x4*)(m1 + 4);
#pragma unroll
    for (int r = 0; r < 4; ++r) {
      float g0 = msgg[off + r]     + be[off + r];
      float g1 = msgg[off + 4 + r] + be[off + 4 + r];
      af[kk].s[r]     = f2b(v0[r] + w0[r] + g0);
      af[kk].s[4 + r] = f2b(v1[r] + w1[r] + g1);
    }
  }

  f32x4 acc[8];
#pragma unroll
  for (int nt = 0; nt < 8; ++nt) acc[nt] = (f32x4)0.f;
#pragma unroll
  for (int kk = 0; kk < 4; ++kk) {
    BFrag bf[8];
#pragma unroll
    for (int nt = 0; nt < 8; ++nt)
#pragma unroll
      for (int j = 0; j < 8; ++j)
        bf[nt].s[j] = f2bt(Wo2[(kk*32 + quad*8 + j)*128 + nt*16 + col]);
#pragma unroll
    for (int nt = 0; nt < 8; ++nt) acc[nt] = MFMA16(af[kk].v, bf[nt].v, acc[nt]);
  }

#pragma unroll
  for (int nt = 0; nt < 8; ++nt) {
    float bv = bo2[nt*16 + col];
#pragma unroll
    for (int r = 0; r < 4; ++r) {
      int row = j0 + quad*4 + r;
      long idx = (long)(b*512 + row)*128 + nt*16 + col;
      float v = h1[idx] + acc[nt][r] + bv;
      out[idx] = v < 0.f ? 0.f : v;
    }
  }
}

// ---------------------------------------------------------------------------
extern "C" void kernel_launch(void* const* d_in, const int* in_sizes, int n_in,
                              void* d_out, int out_size, void* d_ws, size_t ws_size,
                              hipStream_t stream)
{
  const float* node   = (const float*)d_in[0];
  const float* E      = (const float*)d_in[1];
  const float* graph  = (const float*)d_in[2];
  const float* adj    = (const float*)d_in[3];
  const float* hidden = (const float*)d_in[4];
  const float* W1  = (const float*)d_in[5];
  const float* b1  = (const float*)d_in[6];
  const float* W2  = (const float*)d_in[7];
  const float* b2  = (const float*)d_in[8];
  const float* We  = (const float*)d_in[9];
  const float* be  = (const float*)d_in[10];
  const float* Wg  = (const float*)d_in[11];
  const float* bg  = (const float*)d_in[12];
  const float* Wo1 = (const float*)d_in[13];
  const float* bo1 = (const float*)d_in[14];
  const float* Wo2 = (const float*)d_in[15];
  const float* bo2 = (const float*)d_in[16];
  float* ws  = (float*)d_ws;
  float* out = (float*)d_out;

  hipLaunchKernelGGL(k1_small, dim3(194), dim3(64), 0, stream,
                     node, hidden, graph, W1, b1, W2, b2, Wo1, bo1, Wg, bg, ws);
  hipLaunchKernelGGL(k2_main, dim3(512), dim3(256), 0, stream,
                     E, We, adj, ws + WS_MS2, ws + WS_PART);
  hipLaunchKernelGGL(k3_out, dim3(64), dim3(64), 0, stream,
                     ws, Wo2, be, bo2, out);
}